// Round 16
// baseline (276.437 us; speedup 1.0000x reference)
//
#include <hip/hip_runtime.h>
#include <hip/hip_bf16.h>

typedef __attribute__((ext_vector_type(8))) short bf16x8;
typedef __attribute__((ext_vector_type(4))) float f32x4;
typedef unsigned short ushort_t;

#define HID 2048
#define QKVN 6144
#define SEQ 2048
#define NH 16
#define HD 128
#define QB 128
#define KVB 64

#define GLOBAL_AS __attribute__((address_space(1)))
#define LDS_AS __attribute__((address_space(3)))
typedef LDS_AS const char lds_char;

__device__ __forceinline__ void gload_lds16(const ushort_t* g, ushort_t* l) {
    __builtin_amdgcn_global_load_lds((const GLOBAL_AS unsigned int*)g,
                                     (LDS_AS unsigned int*)l, 16, 0, 0);
}

// ds_read_b128 with compile-time offset immediate; opaque to waitcnt pass (r7 win).
template <int OFF>
__device__ __forceinline__ bf16x8 dsr128o(lds_char* p) {
    bf16x8 r;
    asm volatile("ds_read_b128 %0, %1 offset:%2" : "=v"(r) : "v"(p), "i"(OFF));
    return r;
}

__device__ __forceinline__ ushort_t f2b(float f) {
    union { float f; unsigned int u; } x; x.f = f;
    unsigned int r = x.u + 0x7fffu + ((x.u >> 16) & 1u);  // RNE
    return (ushort_t)(r >> 16);
}

#define BARX() asm volatile("s_barrier" ::: "memory")
#define LGKM0() asm volatile("s_waitcnt lgkmcnt(0)" ::: "memory")
#define VMC0() asm volatile("s_waitcnt vmcnt(0)" ::: "memory")

// ---------------- cast fp32 -> bf16 (vectorized) ----------------
__global__ __launch_bounds__(256) void castbf(const float* __restrict__ in,
                                              ushort_t* __restrict__ out, int n) {
    int i = (blockIdx.x * 256 + threadIdx.x) * 8;
    if (i >= n) return;
    float4 a = *(const float4*)(in + i);
    float4 b = *(const float4*)(in + i + 4);
    union { ushort_t u[8]; uint4 v; } r;
    r.u[0] = f2b(a.x); r.u[1] = f2b(a.y); r.u[2] = f2b(a.z); r.u[3] = f2b(a.w);
    r.u[4] = f2b(b.x); r.u[5] = f2b(b.y); r.u[6] = f2b(b.z); r.u[7] = f2b(b.w);
    *(uint4*)(out + i) = r.v;
}

// ------------- transpose + cast: fp32 K x N  ->  bf16 N x K -------------
__global__ __launch_bounds__(256) void transcast(const float* __restrict__ in,
                                                 ushort_t* __restrict__ out,
                                                 int Kd, int Nd) {
    __shared__ float tile[32][33];
    int tx = threadIdx.x & 31, ty = threadIdx.x >> 5;
    int n0 = blockIdx.x * 32, k0 = blockIdx.y * 32;
    for (int j = 0; j < 4; j++)
        tile[ty + 8 * j][tx] = in[(size_t)(k0 + ty + 8 * j) * Nd + n0 + tx];
    __syncthreads();
    for (int j = 0; j < 4; j++)
        out[(size_t)(n0 + ty + 8 * j) * Kd + k0 + tx] = f2b(tile[tx][ty + 8 * j]);
}

// ------------- GEMM 128x(NFRAG*32), BK=32, 3 buffers, 256-thread blocks, 2 blocks/CU -------------
// C(MxN) = A(MxK,bf16) * BT(NxK,bf16)^T, K=2048 (NKT=64) fixed.
// 4 waves (2x2), wave tile 64x(NFRAG*16). LDS: qkv 60KB, outproj 48KB -> 2 independent
// blocks/CU with SEPARATE barriers: blocks drift anti-phase, so one block's MFMA burst
// overlaps the other's LDS-read burst (r15's lockstep serialization broken at block level;
// no VGPR cap needed: natural ~200 < 256 @ 2 waves/SIMD).
// Schedule (r13-proven): step k = lgkm0 -> bar -> READS(k+1 frags, alt reg set, buf (k+1)%3)
// -> STAGES(k+3 -> buf k%3) -> vmcnt(LPS) -> sched_barrier -> MFMA(k). 6-step unroll x10 +
// 4-step tail (dead re-stages of tile 63). Granule swizzle g^((r>>1)&3) (r9: 0 conflicts;
// source sg=(t&3)^((t>>3)&3) valid for all sx since sub-rows advance by 64).
template <int NFRAG, bool OUT_BF16, bool FUSE_V>
__global__ __launch_bounds__(256, 2) void gemmpl(const ushort_t* __restrict__ A,
                                                 const ushort_t* __restrict__ BT,
                                                 void* __restrict__ C,
                                                 ushort_t* __restrict__ vT,
                                                 int M, int N, int K,
                                                 int scale_cols, float scale) {
    __shared__ __align__(16) ushort_t As[3][128 * 32];            // 24 KB
    __shared__ __align__(16) ushort_t Bs[3][NFRAG * 32 * 32];     // qkv 36 KB / outproj 24 KB

    const int t = threadIdx.x;
    const int l = t & 63, w = t >> 6;          // 4 waves
    const int wm = w >> 1, wn = w & 1;         // 2 x 2
    const int lr = l & 15, lg = l >> 4;

    // XCD-aware bijective swizzle (grids 1024 / 512, both % 8 == 0)
    const int nwg = gridDim.x;
    const int cpx = nwg >> 3;
    const int swb = (blockIdx.x & 7) * cpx + (blockIdx.x >> 3);
    const int BN = NFRAG * 32;
    const int NTN = N / BN;
    const int m0 = (swb / NTN) << 7, n0 = (swb % NTN) * BN;

    f32x4 acc[4][NFRAG] = {};
    bf16x8 afA[4], bfA[NFRAG], afB[4], bfB[NFRAG];

    // ---- stage pointers (swizzled source granule baked in); advance by literals ----
    const int sr = t >> 2, sg = (t & 3) ^ ((t >> 3) & 3);
    const ushort_t* aP0 = A + (size_t)(m0 + sr) * K + (sg << 3);
    const ushort_t* aP1 = A + (size_t)(m0 + 64 + sr) * K + (sg << 3);
    const ushort_t* bP0 = BT + (size_t)(n0 + sr) * K + (sg << 3);
    const ushort_t* bP1 = BT + (size_t)(n0 + 64 + sr) * K + (sg << 3);
    const ushort_t* bP2 = (NFRAG == 6) ? BT + (size_t)(n0 + 128 + sr) * K + (sg << 3) : nullptr;

    // ---- precomputed LDS read bases ----
    const int co_ = (lg ^ ((lr >> 1) & 3)) << 4;
    const int aoff = (wm * 64 + lr) * 64 + co_;
    const int boff = (wn * (NFRAG * 16) + lr) * 64 + co_;
    lds_char* aR0 = (lds_char*)&As[0][0] + aoff;
    lds_char* aR1 = (lds_char*)&As[1][0] + aoff;
    lds_char* aR2 = (lds_char*)&As[2][0] + aoff;
    lds_char* bR0 = (lds_char*)&Bs[0][0] + boff;
    lds_char* bR1 = (lds_char*)&Bs[1][0] + boff;
    lds_char* bR2 = (lds_char*)&Bs[2][0] + boff;

#define GLO(G, L)                                                               \
    __builtin_amdgcn_global_load_lds((const GLOBAL_AS unsigned int*)(G),        \
                                     (LDS_AS unsigned int*)(L), 16, 0, 0)

// OFFE: element offset (literal) from current stage base = (tile - base_tile)*32
#define STAGES(SB, OFFE)                                                        \
    do {                                                                        \
        GLO(aP0 + (OFFE), &As[SB][t * 8]);                                      \
        GLO(aP1 + (OFFE), &As[SB][(256 + t) * 8]);                              \
        GLO(bP0 + (OFFE), &Bs[SB][t * 8]);                                      \
        GLO(bP1 + (OFFE), &Bs[SB][(256 + t) * 8]);                              \
        if constexpr (NFRAG == 6) GLO(bP2 + (OFFE), &Bs[SB][(512 + t) * 8]);    \
    } while (0)

#define READS(AF, BF, AR, BR)                                                   \
    do {                                                                        \
        AF[0] = dsr128o<0>(AR);    AF[1] = dsr128o<1024>(AR);                   \
        AF[2] = dsr128o<2048>(AR); AF[3] = dsr128o<3072>(AR);                   \
        BF[0] = dsr128o<0>(BR);    BF[1] = dsr128o<1024>(BR);                   \
        BF[2] = dsr128o<2048>(BR); BF[3] = dsr128o<3072>(BR);                   \
        if constexpr (NFRAG == 6) {                                             \
            BF[4] = dsr128o<4096>(BR); BF[5] = dsr128o<5120>(BR);               \
        }                                                                       \
    } while (0)

#define VMCL()                                                                      \
    do { if constexpr (NFRAG == 6) asm volatile("s_waitcnt vmcnt(5)" ::: "memory"); \
         else                      asm volatile("s_waitcnt vmcnt(4)" ::: "memory"); } while (0)
#define VMC2L()                                                                      \
    do { if constexpr (NFRAG == 6) asm volatile("s_waitcnt vmcnt(10)" ::: "memory"); \
         else                      asm volatile("s_waitcnt vmcnt(8)" ::: "memory"); } while (0)

#define MFMAS(AF, BF)                                                           \
    do {                                                                        \
        __builtin_amdgcn_s_setprio(1);                                          \
        _Pragma("unroll") for (int mi = 0; mi < 4; mi++)                        \
            _Pragma("unroll") for (int nj = 0; nj < NFRAG; nj++)                \
                acc[mi][nj] = __builtin_amdgcn_mfma_f32_16x16x32_bf16(          \
                    AF[mi], BF[nj], acc[mi][nj], 0, 0, 0);                      \
        __builtin_amdgcn_s_setprio(0);                                          \
    } while (0)

#define STEP(SB, AR, BR, AFU, BFU, AFV, BFV, OFFE)                              \
    {                                                                           \
        LGKM0();                                                                \
        __builtin_amdgcn_sched_barrier(0);                                      \
        BARX();                                                                 \
        READS(AFV, BFV, AR, BR);                                                \
        STAGES(SB, OFFE);                                                       \
        VMCL();                                                                 \
        __builtin_amdgcn_sched_barrier(0);                                      \
        MFMAS(AFU, BFU);                                                        \
    }

    // prologue: stage tiles 0,1,2; drain tile0; barrier; read frags(0); drain tile1
    STAGES(0, 0);
    STAGES(1, 32);
    STAGES(2, 64);
    aP0 += 96; aP1 += 96; bP0 += 96; bP1 += 96;
    if constexpr (NFRAG == 6) bP2 += 96;
    VMC2L();
    BARX();
    READS(afA, bfA, aR0, bR0);
    VMCL();

    // 10 blocks of 6 steps (kt = 6it .. 6it+5); stage base corresponds to kt=6it+3
#pragma unroll 1
    for (int it = 0; it < 10; it++) {
        STEP(0, aR1, bR1, afA, bfA, afB, bfB, 0);
        STEP(1, aR2, bR2, afB, bfB, afA, bfA, 32);
        STEP(2, aR0, bR0, afA, bfA, afB, bfB, 64);
        STEP(0, aR1, bR1, afB, bfB, afA, bfA, 96);
        STEP(1, aR2, bR2, afA, bfA, afB, bfB, 128);
        STEP(2, aR0, bR0, afB, bfB, afA, bfA, 160);
        aP0 += 192; aP1 += 192; bP0 += 192; bP1 += 192;
        if constexpr (NFRAG == 6) bP2 += 192;
    }
    // tail: kt = 60,61,62,63 (stage base at tile 63; 61/62 re-stage tile 63, dead)
    STEP(0, aR1, bR1, afA, bfA, afB, bfB, 0);
    STEP(1, aR2, bR2, afB, bfB, afA, bfA, 0);
    STEP(2, aR0, bR0, afA, bfA, afB, bfB, 0);
    LGKM0();
    __builtin_amdgcn_sched_barrier(0);
    VMC0();
    MFMAS(afB, bfB);

#undef STEP
#undef MFMAS
#undef VMCL
#undef VMC2L
#undef READS
#undef STAGES
#undef GLO

    // epilogue
#pragma unroll
    for (int mi = 0; mi < 4; mi++)
#pragma unroll
        for (int nj = 0; nj < NFRAG; nj++) {
            const int row = m0 + wm * 64 + mi * 16 + lg * 4;
            const int col = n0 + wn * (NFRAG * 16) + nj * 16 + lr;
            const f32x4 v = acc[mi][nj];
            if (FUSE_V && col >= 2 * HID) {
                const int c = col - 2 * HID;            // h = c>>7, d = c&127
                const int b_ = row >> 11, s_ = row & 2047;
                union { ushort_t u[4]; uint2 q; } pk;
#pragma unroll
                for (int j = 0; j < 4; j++) pk.u[j] = f2b(v[j]);
                *(uint2*)&vT[((size_t)(b_ * NH + (c >> 7)) * HD + (c & 127)) * SEQ + s_] = pk.q;
            } else {
                const float sc = (col < scale_cols) ? scale : 1.0f;
#pragma unroll
                for (int j = 0; j < 4; j++) {
                    if (OUT_BF16)
                        ((ushort_t*)C)[(size_t)(row + j) * N + col] = f2b(v[j] * sc);
                    else
                        ((float*)C)[(size_t)(row + j) * N + col] = v[j] * sc;
                }
            }
        }
}

// ------------- flash attention v4: 64KB LDS (Ks single, Vs dbuf) for 2 blocks/CU -------------
__global__ __launch_bounds__(512, 1) void attn_fwd4(const ushort_t* __restrict__ qkvb,
                                                    const ushort_t* __restrict__ vT,
                                                    ushort_t* __restrict__ attnb) {
    __shared__ __align__(16) ushort_t Ks[64 * 128];      // 16 KB (single)
    __shared__ __align__(16) ushort_t Vs[2][128 * 64];   // 32 KB
    __shared__ __align__(16) ushort_t Ps[8][16 * 64];    // 16 KB

    const int t = threadIdx.x;
    const int l = t & 63, w = t >> 6;
    const int lr = l & 15, lg = l >> 4;
    const int pr = blockIdx.x, h = blockIdx.y, b = blockIdx.z;

    const ushort_t* kg = qkvb + (size_t)(b * SEQ) * QKVN + HID + h * HD;
    const ushort_t* vg = vT + (size_t)(b * NH + h) * HD * SEQ;

    char* PsB = (char*)Ps[w];
    const int pssz = ((lr & 7) ^ ((lr >> 3) << 1)) << 4;

    const int kcA = 2 * w, kcB = 2 * w + 1;
    const int krA = 8 * w + (l >> 4), krB = krA + 4;
    const int kcolA = ((l & 15) ^ (l >> 4)) << 3;
    const int kcolB = ((l & 15) ^ (4 + (l >> 4))) << 3;
    const int vrA = 16 * w + (l >> 3), vrB = vrA + 8;
    const int vcol = ((l & 7) ^ (l >> 3)) << 3;

    for (int seg = 0; seg < 2; seg++) {
        const int qt = (seg == 0) ? pr : 15 - pr;
        const int q0 = qt * QB;
        const int q0w = q0 + w * 16;
        const int NT = (q0 + QB) / KVB;

        bf16x8 qf[4];
        {
            const ushort_t* qb = qkvb + (size_t)(b * SEQ + q0w + lr) * QKVN + h * HD + lg * 8;
#pragma unroll
            for (int kc = 0; kc < 4; kc++) qf[kc] = *(const bf16x8*)(qb + kc * 32);
        }
        f32x4 o[8] = {};
        float m[4] = {-3e38f, -3e38f, -3e38f, -3e38f};
        float ls[4] = {0.f, 0.f, 0.f, 0.f};

        __syncthreads();  // previous segment's LDS readers done
        gload_lds16(kg + (size_t)krA * QKVN + kcolA, &Ks[kcA * 512 + l * 8]);
        gload_lds16(kg + (size_t)krB * QKVN + kcolB, &Ks[kcB * 512 + l * 8]);
        gload_lds16(vg + (size_t)vrA * SEQ + vcol,   &Vs[0][kcA * 512 + l * 8]);
        gload_lds16(vg + (size_t)vrB * SEQ + vcol,   &Vs[0][kcB * 512 + l * 8]);

        for (int kt = 0; kt < NT; kt++) {
            const int kv0 = kt * KVB;
            __syncthreads();  // A: K(kt)/V(kt) landed; all prior reads done
            if (kt + 1 < NT) {
                const int nb = (kt + 1) & 1;
                const int nkv = kv0 + KVB;
                gload_lds16(vg + (size_t)vrA * SEQ + nkv + vcol, &Vs[nb][kcA * 512 + l * 8]);
                gload_lds16(vg + (size_t)vrB * SEQ + nkv + vcol, &Vs[nb][kcB * 512 + l * 8]);
            }
            const bool act = (kv0 <= q0w + 15);  // wave-uniform

            f32x4 s[4];
            const int rs = (lr & 7) << 4;
            if (act) {
                const char* KsB = (const char*)Ks;
#pragma unroll
                for (int nf = 0; nf < 4; nf++) {
                    const int r = nf * 16 + lr;
                    s[nf] = (f32x4){0.f, 0.f, 0.f, 0.f};
#pragma unroll
                    for (int kc = 0; kc < 4; kc++) {
                        bf16x8 kf = *(const bf16x8*)(KsB + r * 256 + ((kc * 64 + lg * 16) ^ rs));
                        s[nf] = __builtin_amdgcn_mfma_f32_16x16x32_bf16(qf[kc], kf, s[nf], 0, 0, 0);
                    }
                }
            }
            __syncthreads();  // A2: all waves' QK reads of Ks done -> safe to restage Ks
            if (kt + 1 < NT) {
                const int nkv = kv0 + KVB;
                gload_lds16(kg + (size_t)(nkv + krA) * QKVN + kcolA, &Ks[kcA * 512 + l * 8]);
                gload_lds16(kg + (size_t)(nkv + krB) * QKVN + kcolB, &Ks[kcB * 512 + l * 8]);
            }
            if (!act) continue;

            const char* VsB = (const char*)Vs[kt & 1];
            const bool diag = (kv0 + 63 > q0w);
            float tm[4];
#pragma unroll
            for (int j = 0; j < 4; j++) {
                if (diag) {
                    const int qpos = q0w + lg * 4 + j;
#pragma unroll
                    for (int nf = 0; nf < 4; nf++)
                        if (kv0 + nf * 16 + lr > qpos) s[nf][j] = -3e38f;
                }
                tm[j] = fmaxf(fmaxf(s[0][j], s[1][j]), fmaxf(s[2][j], s[3][j]));
#pragma unroll
                for (int mk = 1; mk < 16; mk <<= 1)
                    tm[j] = fmaxf(tm[j], __shfl_xor(tm[j], mk, 64));
            }

            float grow = fmaxf(fmaxf(tm[0] - m[0], tm[1] - m[1]),
                               fmaxf(tm[2] - m[2], tm[3] - m[3]));
            if (!__all(grow <= 8.0f)) {
#pragma unroll
                for (int j = 0; j < 4; j++) {
                    const float mn = fmaxf(m[j], tm[j]);
                    const float fac = exp2f((m[j] - mn) * 1.44269504f);
                    m[j] = mn; ls[j] *= fac;
#pragma unroll
                    for (int nf2 = 0; nf2 < 8; nf2++) o[nf2][j] *= fac;
                }
            }

#pragma unroll
            for (int j = 0; j < 4; j++) {
                const int row = lg * 4 + j;
                const int rsz = ((row & 7) ^ ((row >> 3) << 1)) << 4;
                float psum = 0.f;
#pragma unroll
                for (int nf = 0; nf < 4; nf++) {
                    float p = exp2f((s[nf][j] - m[j]) * 1.44269504f);
                    psum += p;
                    union { float f; unsigned u; } cv; cv.f = p;
                    *(ushort_t*)(PsB + row * 128 + ((nf * 32 + lr * 2) ^ rsz)) = (ushort_t)(cv.u >> 16);
                }
                ls[j] += psum;
            }

            bf16x8 pa0 = *(const bf16x8*)(PsB + lr * 128 + ((lg * 16) ^ pssz));
            bf16x8 pa1 = *(const bf16x8*)(PsB + lr * 128 + ((64 + lg * 16) ^ pssz));
#pragma unroll
            for (int nf2 = 0; nf2 < 8; nf2++) {
                const int vr2 = nf2 * 16 + lr;
                bf16x8 vb0 = *(const bf16x8*)(VsB + vr2 * 128 + ((lg * 16) ^ rs));
                bf16x8 vb1 = *(const bf16x8*)(VsB + vr2 * 128 + ((64 + lg * 16) ^ rs));
                o[nf2] = __builtin_amdgcn_mfma_f32_16x16x32_bf16(pa0, vb0, o[nf2], 0, 0, 0);
                o[nf2] = __builtin_amdgcn_mfma_f32_16x16x32_bf16(pa1, vb1, o[nf2], 0, 0, 0);
            }
        }

        float inv[4];
#pragma unroll
        for (int j = 0; j < 4; j++) {
            float sum = ls[j];
#pragma unroll
            for (int mk = 1; mk < 16; mk <<= 1) sum += __shfl_xor(sum, mk, 64);
            inv[j] = 1.0f / sum;
        }
        ushort_t* ob = attnb + (size_t)(b * SEQ + q0w) * HID + h * HD;
#pragma unroll
        for (int nf2 = 0; nf2 < 8; nf2++)
#pragma unroll
            for (int j = 0; j < 4; j++)
                ob[(size_t)(lg * 4 + j) * HID + nf2 * 16 + lr] = f2b(o[nf2][j] * inv[j]);
    }
}

extern "C" void kernel_launch(void* const* d_in, const int* in_sizes, int n_in,
                              void* d_out, int out_size, void* d_ws, size_t ws_size,
                              hipStream_t stream) {
    const float* x     = (const float*)d_in[0];
    const float* w_qkv = (const float*)d_in[1];
    const float* w_out = (const float*)d_in[2];
    float* out = (float*)d_out;

    // Layout note: every GEMM-staged buffer is followed by another mapped buffer —
    // dead tail stages read <=192B past the end (never consumed).
    char* ws = (char*)d_ws;
    ushort_t* xb    = (ushort_t*)(ws);                 // 4096x2048 bf16
    ushort_t* wqkvT = (ushort_t*)(ws + 16777216);      // 6144x2048 bf16
    ushort_t* woutT = (ushort_t*)(ws + 41943040);      // 2048x2048 bf16
    ushort_t* qkvb  = (ushort_t*)(ws + 50331648);      // 4096x6144 bf16 (V third unused)
    ushort_t* attnb = (ushort_t*)(ws + 100663296);     // 4096x2048 bf16
    ushort_t* vT    = (ushort_t*)(ws + 117440512);     // [b][h][d][s] bf16

    const int M = 2 * SEQ;  // 4096

    castbf<<<(M * HID) / (256 * 8), 256, 0, stream>>>(x, xb, M * HID);
    transcast<<<dim3(QKVN / 32, HID / 32), 256, 0, stream>>>(w_qkv, wqkvT, HID, QKVN);
    transcast<<<dim3(HID / 32, HID / 32), 256, 0, stream>>>(w_out, woutT, HID, HID);

    // qkv = x @ w_qkv, Q pre-scaled; V written transposed to vT; 1024 blocks (2/CU, 2 rounds)
    gemmpl<6, true, true><<<(M / 128) * (QKVN / 192), 256, 0, stream>>>(
        xb, wqkvT, qkvb, vT, M, QKVN, HID, HID, 0.08838834764831845f);

    attn_fwd4<<<dim3(8, NH, 2), 512, 0, stream>>>(qkvb, vT, attnb);

    // out = attn @ w_out; 128x128 tile, 512 blocks (2/CU, 1 round)
    gemmpl<4, false, false><<<(M / 128) * (HID / 128), 256, 0, stream>>>(
        attnb, woutT, out, nullptr, M, HID, HID, 0, 1.0f);
}

// Round 17
// 260.508 us; speedup vs baseline: 1.0611x; 1.0611x over previous
//
#include <hip/hip_runtime.h>
#include <hip/hip_bf16.h>

typedef __attribute__((ext_vector_type(8))) short bf16x8;
typedef __attribute__((ext_vector_type(4))) float f32x4;
typedef unsigned short ushort_t;

#define HID 2048
#define QKVN 6144
#define SEQ 2048
#define NH 16
#define HD 128
#define QB 128
#define KVB 64

#define GLOBAL_AS __attribute__((address_space(1)))
#define LDS_AS __attribute__((address_space(3)))
typedef LDS_AS const char lds_char;

__device__ __forceinline__ void gload_lds16(const ushort_t* g, ushort_t* l) {
    __builtin_amdgcn_global_load_lds((const GLOBAL_AS unsigned int*)g,
                                     (LDS_AS unsigned int*)l, 16, 0, 0);
}

// ds_read_b128 with compile-time offset immediate; opaque to waitcnt pass (r7 win).
template <int OFF>
__device__ __forceinline__ bf16x8 dsr128o(lds_char* p) {
    bf16x8 r;
    asm volatile("ds_read_b128 %0, %1 offset:%2" : "=v"(r) : "v"(p), "i"(OFF));
    return r;
}

__device__ __forceinline__ ushort_t f2b(float f) {
    union { float f; unsigned int u; } x; x.f = f;
    unsigned int r = x.u + 0x7fffu + ((x.u >> 16) & 1u);  // RNE
    return (ushort_t)(r >> 16);
}

#define BARX() asm volatile("s_barrier" ::: "memory")
#define LGKM0() asm volatile("s_waitcnt lgkmcnt(0)" ::: "memory")
#define VMC0() asm volatile("s_waitcnt vmcnt(0)" ::: "memory")

// ---------------- cast fp32 -> bf16 (vectorized) ----------------
__global__ __launch_bounds__(256) void castbf(const float* __restrict__ in,
                                              ushort_t* __restrict__ out, int n) {
    int i = (blockIdx.x * 256 + threadIdx.x) * 8;
    if (i >= n) return;
    float4 a = *(const float4*)(in + i);
    float4 b = *(const float4*)(in + i + 4);
    union { ushort_t u[8]; uint4 v; } r;
    r.u[0] = f2b(a.x); r.u[1] = f2b(a.y); r.u[2] = f2b(a.z); r.u[3] = f2b(a.w);
    r.u[4] = f2b(b.x); r.u[5] = f2b(b.y); r.u[6] = f2b(b.z); r.u[7] = f2b(b.w);
    *(uint4*)(out + i) = r.v;
}

// ------------- transpose + cast: fp32 K x N  ->  bf16 N x K -------------
__global__ __launch_bounds__(256) void transcast(const float* __restrict__ in,
                                                 ushort_t* __restrict__ out,
                                                 int Kd, int Nd) {
    __shared__ float tile[32][33];
    int tx = threadIdx.x & 31, ty = threadIdx.x >> 5;
    int n0 = blockIdx.x * 32, k0 = blockIdx.y * 32;
    for (int j = 0; j < 4; j++)
        tile[ty + 8 * j][tx] = in[(size_t)(k0 + ty + 8 * j) * Nd + n0 + tx];
    __syncthreads();
    for (int j = 0; j < 4; j++)
        out[(size_t)(n0 + ty + 8 * j) * Kd + k0 + tx] = f2b(tile[tx][ty + 8 * j]);
}

// ------------- GEMM 128x(NFRAG*64), BK=32, 3 buffers, compile-time schedule -------------
// (r13/r15-proven structure: (512,1), 3 rotating buffers, 6-step unroll.)
// r17 change: block->tile map is M-MAJOR so each XCD's contiguous chunk of blocks
// shares a small set of B panels (L2-resident, ~3MB) while A streams — r15's n-major
// map cycled 24MB of B through each 4MB XCD L2 (FETCH 205MB ~= B x 8 XCDs).
template <int NFRAG, bool OUT_BF16, bool FUSE_V>
__global__ __launch_bounds__(512, 1) void gemmpl(const ushort_t* __restrict__ A,
                                                 const ushort_t* __restrict__ BT,
                                                 void* __restrict__ C,
                                                 ushort_t* __restrict__ vT,
                                                 int M, int N, int K,
                                                 int scale_cols, float scale) {
    __shared__ __align__(16) ushort_t As[3][128 * 32];
    __shared__ __align__(16) ushort_t Bs[3][NFRAG * 64 * 32];

    const int t = threadIdx.x;
    const int l = t & 63, w = t >> 6;
    const int wm = w >> 2, wn = w & 3;
    const int lr = l & 15, lg = l >> 4;

    // XCD-aware bijective swizzle (grids 512 / 256, both % 8 == 0)
    const int nwg = gridDim.x;
    const int cpx = nwg >> 3;
    const int swb = (blockIdx.x & 7) * cpx + (blockIdx.x >> 3);
    const int BN = NFRAG * 64;
    const int NTM = M >> 7;                 // m-tiles (32)
    const int m0 = (swb % NTM) << 7;        // m-major: consecutive swb share n0
    const int n0 = (swb / NTM) * BN;

    f32x4 acc[4][NFRAG] = {};
    bf16x8 afA[4], bfA[NFRAG], afB[4], bfB[NFRAG];

    // ---- stage pointers (swizzled source granule baked in); advance by literals ----
    const int sr = t >> 2, sg = (t & 3) ^ ((t >> 3) & 3);
    const ushort_t* aP  = A  + (size_t)(m0 + sr) * K + (sg << 3);
    const ushort_t* bP0 = BT + (size_t)(n0 + sr) * K + (sg << 3);
    const ushort_t* bP1 = BT + (size_t)(n0 + 128 + sr) * K + (sg << 3);
    const ushort_t* bP2 = (NFRAG == 6) ? BT + (size_t)(n0 + 256 + sr) * K + (sg << 3) : nullptr;

    // ---- precomputed LDS read bases ----
    const int co_ = (lg ^ ((lr >> 1) & 3)) << 4;
    const int aoff = (wm * 64 + lr) * 64 + co_;
    const int boff = (wn * (NFRAG * 16) + lr) * 64 + co_;
    lds_char* aR0 = (lds_char*)&As[0][0] + aoff;
    lds_char* aR1 = (lds_char*)&As[1][0] + aoff;
    lds_char* aR2 = (lds_char*)&As[2][0] + aoff;
    lds_char* bR0 = (lds_char*)&Bs[0][0] + boff;
    lds_char* bR1 = (lds_char*)&Bs[1][0] + boff;
    lds_char* bR2 = (lds_char*)&Bs[2][0] + boff;

#define GLO(G, L)                                                               \
    __builtin_amdgcn_global_load_lds((const GLOBAL_AS unsigned int*)(G),        \
                                     (LDS_AS unsigned int*)(L), 16, 0, 0)

// OFFE: element offset (literal) from current stage base = (tile - base_tile)*32
#define STAGES(SB, OFFE)                                                        \
    do {                                                                        \
        GLO(aP + (OFFE),  &As[SB][t * 8]);                                      \
        GLO(bP0 + (OFFE), &Bs[SB][t * 8]);                                      \
        GLO(bP1 + (OFFE), &Bs[SB][(512 + t) * 8]);                              \
        if constexpr (NFRAG == 6) GLO(bP2 + (OFFE), &Bs[SB][(1024 + t) * 8]);   \
    } while (0)

#define READS(AF, BF, AR, BR)                                                   \
    do {                                                                        \
        AF[0] = dsr128o<0>(AR);    AF[1] = dsr128o<1024>(AR);                   \
        AF[2] = dsr128o<2048>(AR); AF[3] = dsr128o<3072>(AR);                   \
        BF[0] = dsr128o<0>(BR);    BF[1] = dsr128o<1024>(BR);                   \
        BF[2] = dsr128o<2048>(BR); BF[3] = dsr128o<3072>(BR);                   \
        if constexpr (NFRAG == 6) {                                             \
            BF[4] = dsr128o<4096>(BR); BF[5] = dsr128o<5120>(BR);               \
        }                                                                       \
    } while (0)

#define VMCL()                                                                      \
    do { if constexpr (NFRAG == 6) asm volatile("s_waitcnt vmcnt(4)" ::: "memory"); \
         else                      asm volatile("s_waitcnt vmcnt(3)" ::: "memory"); } while (0)
#define VMC2L()                                                                     \
    do { if constexpr (NFRAG == 6) asm volatile("s_waitcnt vmcnt(8)" ::: "memory"); \
         else                      asm volatile("s_waitcnt vmcnt(6)" ::: "memory"); } while (0)

#define MFMAS(AF, BF)                                                           \
    do {                                                                        \
        __builtin_amdgcn_s_setprio(1);                                          \
        _Pragma("unroll") for (int mi = 0; mi < 4; mi++)                        \
            _Pragma("unroll") for (int nj = 0; nj < NFRAG; nj++)                \
                acc[mi][nj] = __builtin_amdgcn_mfma_f32_16x16x32_bf16(          \
                    AF[mi], BF[nj], acc[mi][nj], 0, 0, 0);                      \
        __builtin_amdgcn_s_setprio(0);                                          \
    } while (0)

#define STEP(SB, AR, BR, AFU, BFU, AFV, BFV, OFFE)                              \
    {                                                                           \
        LGKM0();                                                                \
        __builtin_amdgcn_sched_barrier(0);                                      \
        BARX();                                                                 \
        READS(AFV, BFV, AR, BR);                                                \
        STAGES(SB, OFFE);                                                       \
        VMCL();                                                                 \
        __builtin_amdgcn_sched_barrier(0);                                      \
        MFMAS(AFU, BFU);                                                        \
    }

    // prologue: stage tiles 0,1,2; drain tile0; barrier; read frags(0); drain tile1
    STAGES(0, 0);
    STAGES(1, 32);
    STAGES(2, 64);
    aP += 96; bP0 += 96; bP1 += 96;
    if constexpr (NFRAG == 6) bP2 += 96;
    VMC2L();
    BARX();
    READS(afA, bfA, aR0, bR0);
    VMCL();

    // 10 blocks of 6 steps (kt = 6it .. 6it+5); stage base corresponds to kt=6it+3
#pragma unroll 1
    for (int it = 0; it < 10; it++) {
        STEP(0, aR1, bR1, afA, bfA, afB, bfB, 0);
        STEP(1, aR2, bR2, afB, bfB, afA, bfA, 32);
        STEP(2, aR0, bR0, afA, bfA, afB, bfB, 64);
        STEP(0, aR1, bR1, afB, bfB, afA, bfA, 96);
        STEP(1, aR2, bR2, afA, bfA, afB, bfB, 128);
        STEP(2, aR0, bR0, afB, bfB, afA, bfA, 160);
        aP += 192; bP0 += 192; bP1 += 192;
        if constexpr (NFRAG == 6) bP2 += 192;
    }
    // tail: kt = 60,61,62,63 (stage base at tile 63; 61/62 re-stage tile 63, dead)
    STEP(0, aR1, bR1, afA, bfA, afB, bfB, 0);
    STEP(1, aR2, bR2, afB, bfB, afA, bfA, 0);
    STEP(2, aR0, bR0, afA, bfA, afB, bfB, 0);
    LGKM0();
    __builtin_amdgcn_sched_barrier(0);
    VMC0();
    MFMAS(afB, bfB);

#undef STEP
#undef MFMAS
#undef VMCL
#undef VMC2L
#undef READS
#undef STAGES
#undef GLO

    // epilogue
#pragma unroll
    for (int mi = 0; mi < 4; mi++)
#pragma unroll
        for (int nj = 0; nj < NFRAG; nj++) {
            const int row = m0 + wm * 64 + mi * 16 + lg * 4;
            const int col = n0 + wn * (NFRAG * 16) + nj * 16 + lr;
            const f32x4 v = acc[mi][nj];
            if (FUSE_V && col >= 2 * HID) {
                const int c = col - 2 * HID;            // h = c>>7, d = c&127
                const int b_ = row >> 11, s_ = row & 2047;
                union { ushort_t u[4]; uint2 q; } pk;
#pragma unroll
                for (int j = 0; j < 4; j++) pk.u[j] = f2b(v[j]);
                *(uint2*)&vT[((size_t)(b_ * NH + (c >> 7)) * HD + (c & 127)) * SEQ + s_] = pk.q;
            } else {
                const float sc = (col < scale_cols) ? scale : 1.0f;
#pragma unroll
                for (int j = 0; j < 4; j++) {
                    if (OUT_BF16)
                        ((ushort_t*)C)[(size_t)(row + j) * N + col] = f2b(v[j] * sc);
                    else
                        ((float*)C)[(size_t)(row + j) * N + col] = v[j] * sc;
                }
            }
        }
}

// ------------- flash attention v4: 64KB LDS (Ks single, Vs dbuf) for 2 blocks/CU -------------
__global__ __launch_bounds__(512, 1) void attn_fwd4(const ushort_t* __restrict__ qkvb,
                                                    const ushort_t* __restrict__ vT,
                                                    ushort_t* __restrict__ attnb) {
    __shared__ __align__(16) ushort_t Ks[64 * 128];      // 16 KB (single)
    __shared__ __align__(16) ushort_t Vs[2][128 * 64];   // 32 KB
    __shared__ __align__(16) ushort_t Ps[8][16 * 64];    // 16 KB

    const int t = threadIdx.x;
    const int l = t & 63, w = t >> 6;
    const int lr = l & 15, lg = l >> 4;
    const int pr = blockIdx.x, h = blockIdx.y, b = blockIdx.z;

    const ushort_t* kg = qkvb + (size_t)(b * SEQ) * QKVN + HID + h * HD;
    const ushort_t* vg = vT + (size_t)(b * NH + h) * HD * SEQ;

    char* PsB = (char*)Ps[w];
    const int pssz = ((lr & 7) ^ ((lr >> 3) << 1)) << 4;

    const int kcA = 2 * w, kcB = 2 * w + 1;
    const int krA = 8 * w + (l >> 4), krB = krA + 4;
    const int kcolA = ((l & 15) ^ (l >> 4)) << 3;
    const int kcolB = ((l & 15) ^ (4 + (l >> 4))) << 3;
    const int vrA = 16 * w + (l >> 3), vrB = vrA + 8;
    const int vcol = ((l & 7) ^ (l >> 3)) << 3;

    for (int seg = 0; seg < 2; seg++) {
        const int qt = (seg == 0) ? pr : 15 - pr;
        const int q0 = qt * QB;
        const int q0w = q0 + w * 16;
        const int NT = (q0 + QB) / KVB;

        bf16x8 qf[4];
        {
            const ushort_t* qb = qkvb + (size_t)(b * SEQ + q0w + lr) * QKVN + h * HD + lg * 8;
#pragma unroll
            for (int kc = 0; kc < 4; kc++) qf[kc] = *(const bf16x8*)(qb + kc * 32);
        }
        f32x4 o[8] = {};
        float m[4] = {-3e38f, -3e38f, -3e38f, -3e38f};
        float ls[4] = {0.f, 0.f, 0.f, 0.f};

        __syncthreads();  // previous segment's LDS readers done
        gload_lds16(kg + (size_t)krA * QKVN + kcolA, &Ks[kcA * 512 + l * 8]);
        gload_lds16(kg + (size_t)krB * QKVN + kcolB, &Ks[kcB * 512 + l * 8]);
        gload_lds16(vg + (size_t)vrA * SEQ + vcol,   &Vs[0][kcA * 512 + l * 8]);
        gload_lds16(vg + (size_t)vrB * SEQ + vcol,   &Vs[0][kcB * 512 + l * 8]);

        for (int kt = 0; kt < NT; kt++) {
            const int kv0 = kt * KVB;
            __syncthreads();  // A: K(kt)/V(kt) landed; all prior reads done
            if (kt + 1 < NT) {
                const int nb = (kt + 1) & 1;
                const int nkv = kv0 + KVB;
                gload_lds16(vg + (size_t)vrA * SEQ + nkv + vcol, &Vs[nb][kcA * 512 + l * 8]);
                gload_lds16(vg + (size_t)vrB * SEQ + nkv + vcol, &Vs[nb][kcB * 512 + l * 8]);
            }
            const bool act = (kv0 <= q0w + 15);  // wave-uniform

            f32x4 s[4];
            const int rs = (lr & 7) << 4;
            if (act) {
                const char* KsB = (const char*)Ks;
#pragma unroll
                for (int nf = 0; nf < 4; nf++) {
                    const int r = nf * 16 + lr;
                    s[nf] = (f32x4){0.f, 0.f, 0.f, 0.f};
#pragma unroll
                    for (int kc = 0; kc < 4; kc++) {
                        bf16x8 kf = *(const bf16x8*)(KsB + r * 256 + ((kc * 64 + lg * 16) ^ rs));
                        s[nf] = __builtin_amdgcn_mfma_f32_16x16x32_bf16(qf[kc], kf, s[nf], 0, 0, 0);
                    }
                }
            }
            __syncthreads();  // A2: all waves' QK reads of Ks done -> safe to restage Ks
            if (kt + 1 < NT) {
                const int nkv = kv0 + KVB;
                gload_lds16(kg + (size_t)(nkv + krA) * QKVN + kcolA, &Ks[kcA * 512 + l * 8]);
                gload_lds16(kg + (size_t)(nkv + krB) * QKVN + kcolB, &Ks[kcB * 512 + l * 8]);
            }
            if (!act) continue;

            const char* VsB = (const char*)Vs[kt & 1];
            const bool diag = (kv0 + 63 > q0w);
            float tm[4];
#pragma unroll
            for (int j = 0; j < 4; j++) {
                if (diag) {
                    const int qpos = q0w + lg * 4 + j;
#pragma unroll
                    for (int nf = 0; nf < 4; nf++)
                        if (kv0 + nf * 16 + lr > qpos) s[nf][j] = -3e38f;
                }
                tm[j] = fmaxf(fmaxf(s[0][j], s[1][j]), fmaxf(s[2][j], s[3][j]));
#pragma unroll
                for (int mk = 1; mk < 16; mk <<= 1)
                    tm[j] = fmaxf(tm[j], __shfl_xor(tm[j], mk, 64));
            }

            float grow = fmaxf(fmaxf(tm[0] - m[0], tm[1] - m[1]),
                               fmaxf(tm[2] - m[2], tm[3] - m[3]));
            if (!__all(grow <= 8.0f)) {
#pragma unroll
                for (int j = 0; j < 4; j++) {
                    const float mn = fmaxf(m[j], tm[j]);
                    const float fac = exp2f((m[j] - mn) * 1.44269504f);
                    m[j] = mn; ls[j] *= fac;
#pragma unroll
                    for (int nf2 = 0; nf2 < 8; nf2++) o[nf2][j] *= fac;
                }
            }

#pragma unroll
            for (int j = 0; j < 4; j++) {
                const int row = lg * 4 + j;
                const int rsz = ((row & 7) ^ ((row >> 3) << 1)) << 4;
                float psum = 0.f;
#pragma unroll
                for (int nf = 0; nf < 4; nf++) {
                    float p = exp2f((s[nf][j] - m[j]) * 1.44269504f);
                    psum += p;
                    union { float f; unsigned u; } cv; cv.f = p;
                    *(ushort_t*)(PsB + row * 128 + ((nf * 32 + lr * 2) ^ rsz)) = (ushort_t)(cv.u >> 16);
                }
                ls[j] += psum;
            }

            bf16x8 pa0 = *(const bf16x8*)(PsB + lr * 128 + ((lg * 16) ^ pssz));
            bf16x8 pa1 = *(const bf16x8*)(PsB + lr * 128 + ((64 + lg * 16) ^ pssz));
#pragma unroll
            for (int nf2 = 0; nf2 < 8; nf2++) {
                const int vr2 = nf2 * 16 + lr;
                bf16x8 vb0 = *(const bf16x8*)(VsB + vr2 * 128 + ((lg * 16) ^ rs));
                bf16x8 vb1 = *(const bf16x8*)(VsB + vr2 * 128 + ((64 + lg * 16) ^ rs));
                o[nf2] = __builtin_amdgcn_mfma_f32_16x16x32_bf16(pa0, vb0, o[nf2], 0, 0, 0);
                o[nf2] = __builtin_amdgcn_mfma_f32_16x16x32_bf16(pa1, vb1, o[nf2], 0, 0, 0);
            }
        }

        float inv[4];
#pragma unroll
        for (int j = 0; j < 4; j++) {
            float sum = ls[j];
#pragma unroll
            for (int mk = 1; mk < 16; mk <<= 1) sum += __shfl_xor(sum, mk, 64);
            inv[j] = 1.0f / sum;
        }
        ushort_t* ob = attnb + (size_t)(b * SEQ + q0w) * HID + h * HD;
#pragma unroll
        for (int nf2 = 0; nf2 < 8; nf2++)
#pragma unroll
            for (int j = 0; j < 4; j++)
                ob[(size_t)(lg * 4 + j) * HID + nf2 * 16 + lr] = f2b(o[nf2][j] * inv[j]);
    }
}

extern "C" void kernel_launch(void* const* d_in, const int* in_sizes, int n_in,
                              void* d_out, int out_size, void* d_ws, size_t ws_size,
                              hipStream_t stream) {
    const float* x     = (const float*)d_in[0];
    const float* w_qkv = (const float*)d_in[1];
    const float* w_out = (const float*)d_in[2];
    float* out = (float*)d_out;

    // Layout note: every GEMM-staged buffer is followed by another mapped buffer —
    // dead tail stages read <=192B past the end (never consumed).
    char* ws = (char*)d_ws;
    ushort_t* xb    = (ushort_t*)(ws);                 // 4096x2048 bf16
    ushort_t* wqkvT = (ushort_t*)(ws + 16777216);      // 6144x2048 bf16
    ushort_t* woutT = (ushort_t*)(ws + 41943040);      // 2048x2048 bf16
    ushort_t* qkvb  = (ushort_t*)(ws + 50331648);      // 4096x6144 bf16 (V third unused)
    ushort_t* attnb = (ushort_t*)(ws + 100663296);     // 4096x2048 bf16
    ushort_t* vT    = (ushort_t*)(ws + 117440512);     // [b][h][d][s] bf16

    const int M = 2 * SEQ;  // 4096

    castbf<<<(M * HID) / (256 * 8), 256, 0, stream>>>(x, xb, M * HID);
    transcast<<<dim3(QKVN / 32, HID / 32), 256, 0, stream>>>(w_qkv, wqkvT, HID, QKVN);
    transcast<<<dim3(HID / 32, HID / 32), 256, 0, stream>>>(w_out, woutT, HID, HID);

    // qkv = x @ w_qkv, Q pre-scaled; V written transposed to vT (transV fused away)
    gemmpl<6, true, true><<<(M / 128) * (QKVN / 384), 512, 0, stream>>>(
        xb, wqkvT, qkvb, vT, M, QKVN, HID, HID, 0.08838834764831845f);

    attn_fwd4<<<dim3(8, NH, 2), 512, 0, stream>>>(qkvb, vT, attnb);

    // out = attn @ w_out; 128x256, 256 blocks = 1 round
    gemmpl<4, false, false><<<(M / 128) * (HID / 256), 512, 0, stream>>>(
        attnb, woutT, out, nullptr, M, HID, HID, 0, 1.0f);
}

// Round 18
// 249.815 us; speedup vs baseline: 1.1066x; 1.0428x over previous
//
#include <hip/hip_runtime.h>
#include <hip/hip_bf16.h>

typedef __attribute__((ext_vector_type(8))) short bf16x8;
typedef __attribute__((ext_vector_type(4))) float f32x4;
typedef unsigned short ushort_t;

#define HID 2048
#define QKVN 6144
#define SEQ 2048
#define NH 16
#define HD 128
#define QB 128
#define KVB 64

#define GLOBAL_AS __attribute__((address_space(1)))
#define LDS_AS __attribute__((address_space(3)))
typedef LDS_AS const char lds_char;

__device__ __forceinline__ void gload_lds16(const ushort_t* g, ushort_t* l) {
    __builtin_amdgcn_global_load_lds((const GLOBAL_AS unsigned int*)g,
                                     (LDS_AS unsigned int*)l, 16, 0, 0);
}

// ds_read_b128 with compile-time offset immediate; opaque to waitcnt pass (r7 win).
template <int OFF>
__device__ __forceinline__ bf16x8 dsr128o(lds_char* p) {
    bf16x8 r;
    asm volatile("ds_read_b128 %0, %1 offset:%2" : "=v"(r) : "v"(p), "i"(OFF));
    return r;
}

__device__ __forceinline__ ushort_t f2b(float f) {
    union { float f; unsigned int u; } x; x.f = f;
    unsigned int r = x.u + 0x7fffu + ((x.u >> 16) & 1u);  // RNE
    return (ushort_t)(r >> 16);
}

#define BARX() asm volatile("s_barrier" ::: "memory")
#define LGKM0() asm volatile("s_waitcnt lgkmcnt(0)" ::: "memory")
#define VMC0() asm volatile("s_waitcnt vmcnt(0)" ::: "memory")

// ---------------- cast fp32 -> bf16 (vectorized) ----------------
__global__ __launch_bounds__(256) void castbf(const float* __restrict__ in,
                                              ushort_t* __restrict__ out, int n) {
    int i = (blockIdx.x * 256 + threadIdx.x) * 8;
    if (i >= n) return;
    float4 a = *(const float4*)(in + i);
    float4 b = *(const float4*)(in + i + 4);
    union { ushort_t u[8]; uint4 v; } r;
    r.u[0] = f2b(a.x); r.u[1] = f2b(a.y); r.u[2] = f2b(a.z); r.u[3] = f2b(a.w);
    r.u[4] = f2b(b.x); r.u[5] = f2b(b.y); r.u[6] = f2b(b.z); r.u[7] = f2b(b.w);
    *(uint4*)(out + i) = r.v;
}

// ------------- transpose + cast: fp32 K x N  ->  bf16 N x K -------------
__global__ __launch_bounds__(256) void transcast(const float* __restrict__ in,
                                                 ushort_t* __restrict__ out,
                                                 int Kd, int Nd) {
    __shared__ float tile[32][33];
    int tx = threadIdx.x & 31, ty = threadIdx.x >> 5;
    int n0 = blockIdx.x * 32, k0 = blockIdx.y * 32;
    for (int j = 0; j < 4; j++)
        tile[ty + 8 * j][tx] = in[(size_t)(k0 + ty + 8 * j) * Nd + n0 + tx];
    __syncthreads();
    for (int j = 0; j < 4; j++)
        out[(size_t)(n0 + ty + 8 * j) * Kd + k0 + tx] = f2b(tile[tx][ty + 8 * j]);
}

// ------------- GEMM 128x(NFRAG*64), BK=32, 3 buffers, compile-time schedule -------------
// r15-proven structure (n-major tile map). r18 change: VMCL moved AFTER the MFMA
// cluster — the stage-drain vmcnt(4) previously gated MFMA ISSUE via sched_barrier,
// exposing HBM latency on the matrix pipe every step, although MFMAs never read
// staged data (their operands are covered by the step-top lgkmcnt(0)). The trailing
// VMCL still precedes the next step's barrier, so the drain obligation for READS
// after that barrier (tile k+1, staged at k-2) is preserved. Hazards unchanged.
template <int NFRAG, bool OUT_BF16, bool FUSE_V>
__global__ __launch_bounds__(512, 1) void gemmpl(const ushort_t* __restrict__ A,
                                                 const ushort_t* __restrict__ BT,
                                                 void* __restrict__ C,
                                                 ushort_t* __restrict__ vT,
                                                 int M, int N, int K,
                                                 int scale_cols, float scale) {
    __shared__ __align__(16) ushort_t As[3][128 * 32];
    __shared__ __align__(16) ushort_t Bs[3][NFRAG * 64 * 32];

    const int t = threadIdx.x;
    const int l = t & 63, w = t >> 6;
    const int wm = w >> 2, wn = w & 3;
    const int lr = l & 15, lg = l >> 4;

    // XCD-aware bijective swizzle (grids 512 / 256, both % 8 == 0)
    const int nwg = gridDim.x;
    const int cpx = nwg >> 3;
    const int swb = (blockIdx.x & 7) * cpx + (blockIdx.x >> 3);
    const int BN = NFRAG * 64;
    const int NTN = N / BN;
    const int m0 = (swb / NTN) << 7, n0 = (swb % NTN) * BN;

    f32x4 acc[4][NFRAG] = {};
    bf16x8 afA[4], bfA[NFRAG], afB[4], bfB[NFRAG];

    // ---- stage pointers (swizzled source granule baked in); advance by literals ----
    const int sr = t >> 2, sg = (t & 3) ^ ((t >> 3) & 3);
    const ushort_t* aP  = A  + (size_t)(m0 + sr) * K + (sg << 3);
    const ushort_t* bP0 = BT + (size_t)(n0 + sr) * K + (sg << 3);
    const ushort_t* bP1 = BT + (size_t)(n0 + 128 + sr) * K + (sg << 3);
    const ushort_t* bP2 = (NFRAG == 6) ? BT + (size_t)(n0 + 256 + sr) * K + (sg << 3) : nullptr;

    // ---- precomputed LDS read bases ----
    const int co_ = (lg ^ ((lr >> 1) & 3)) << 4;
    const int aoff = (wm * 64 + lr) * 64 + co_;
    const int boff = (wn * (NFRAG * 16) + lr) * 64 + co_;
    lds_char* aR0 = (lds_char*)&As[0][0] + aoff;
    lds_char* aR1 = (lds_char*)&As[1][0] + aoff;
    lds_char* aR2 = (lds_char*)&As[2][0] + aoff;
    lds_char* bR0 = (lds_char*)&Bs[0][0] + boff;
    lds_char* bR1 = (lds_char*)&Bs[1][0] + boff;
    lds_char* bR2 = (lds_char*)&Bs[2][0] + boff;

#define GLO(G, L)                                                               \
    __builtin_amdgcn_global_load_lds((const GLOBAL_AS unsigned int*)(G),        \
                                     (LDS_AS unsigned int*)(L), 16, 0, 0)

// OFFE: element offset (literal) from current stage base = (tile - base_tile)*32
#define STAGES(SB, OFFE)                                                        \
    do {                                                                        \
        GLO(aP + (OFFE),  &As[SB][t * 8]);                                      \
        GLO(bP0 + (OFFE), &Bs[SB][t * 8]);                                      \
        GLO(bP1 + (OFFE), &Bs[SB][(512 + t) * 8]);                              \
        if constexpr (NFRAG == 6) GLO(bP2 + (OFFE), &Bs[SB][(1024 + t) * 8]);   \
    } while (0)

#define READS(AF, BF, AR, BR)                                                   \
    do {                                                                        \
        AF[0] = dsr128o<0>(AR);    AF[1] = dsr128o<1024>(AR);                   \
        AF[2] = dsr128o<2048>(AR); AF[3] = dsr128o<3072>(AR);                   \
        BF[0] = dsr128o<0>(BR);    BF[1] = dsr128o<1024>(BR);                   \
        BF[2] = dsr128o<2048>(BR); BF[3] = dsr128o<3072>(BR);                   \
        if constexpr (NFRAG == 6) {                                             \
            BF[4] = dsr128o<4096>(BR); BF[5] = dsr128o<5120>(BR);               \
        }                                                                       \
    } while (0)

#define VMCL()                                                                      \
    do { if constexpr (NFRAG == 6) asm volatile("s_waitcnt vmcnt(4)" ::: "memory"); \
         else                      asm volatile("s_waitcnt vmcnt(3)" ::: "memory"); } while (0)
#define VMC2L()                                                                     \
    do { if constexpr (NFRAG == 6) asm volatile("s_waitcnt vmcnt(8)" ::: "memory"); \
         else                      asm volatile("s_waitcnt vmcnt(6)" ::: "memory"); } while (0)

#define MFMAS(AF, BF)                                                           \
    do {                                                                        \
        __builtin_amdgcn_s_setprio(1);                                          \
        _Pragma("unroll") for (int mi = 0; mi < 4; mi++)                        \
            _Pragma("unroll") for (int nj = 0; nj < NFRAG; nj++)                \
                acc[mi][nj] = __builtin_amdgcn_mfma_f32_16x16x32_bf16(          \
                    AF[mi], BF[nj], acc[mi][nj], 0, 0, 0);                      \
        __builtin_amdgcn_s_setprio(0);                                          \
    } while (0)

// r18 step: MFMA issues immediately after reads/stages; stage-drain VMCL trails
// the MFMA cluster (still before the next step's barrier).
#define STEP(SB, AR, BR, AFU, BFU, AFV, BFV, OFFE)                              \
    {                                                                           \
        LGKM0();                                                                \
        __builtin_amdgcn_sched_barrier(0);                                      \
        BARX();                                                                 \
        READS(AFV, BFV, AR, BR);                                                \
        STAGES(SB, OFFE);                                                       \
        __builtin_amdgcn_sched_barrier(0);                                      \
        MFMAS(AFU, BFU);                                                        \
        VMCL();                                                                 \
    }

    // prologue: stage tiles 0,1,2; drain tile0; barrier; read frags(0); drain tile1
    STAGES(0, 0);
    STAGES(1, 32);
    STAGES(2, 64);
    aP += 96; bP0 += 96; bP1 += 96;
    if constexpr (NFRAG == 6) bP2 += 96;
    VMC2L();
    BARX();
    READS(afA, bfA, aR0, bR0);
    VMCL();

    // 10 blocks of 6 steps (kt = 6it .. 6it+5); stage base corresponds to kt=6it+3
#pragma unroll 1
    for (int it = 0; it < 10; it++) {
        STEP(0, aR1, bR1, afA, bfA, afB, bfB, 0);
        STEP(1, aR2, bR2, afB, bfB, afA, bfA, 32);
        STEP(2, aR0, bR0, afA, bfA, afB, bfB, 64);
        STEP(0, aR1, bR1, afB, bfB, afA, bfA, 96);
        STEP(1, aR2, bR2, afA, bfA, afB, bfB, 128);
        STEP(2, aR0, bR0, afB, bfB, afA, bfA, 160);
        aP += 192; bP0 += 192; bP1 += 192;
        if constexpr (NFRAG == 6) bP2 += 192;
    }
    // tail: kt = 60,61,62,63 (stage base at tile 63; 61/62 re-stage tile 63, dead)
    STEP(0, aR1, bR1, afA, bfA, afB, bfB, 0);
    STEP(1, aR2, bR2, afB, bfB, afA, bfA, 0);
    STEP(2, aR0, bR0, afA, bfA, afB, bfB, 0);
    LGKM0();
    __builtin_amdgcn_sched_barrier(0);
    VMC0();
    MFMAS(afB, bfB);

#undef STEP
#undef MFMAS
#undef VMCL
#undef VMC2L
#undef READS
#undef STAGES
#undef GLO

    // epilogue
#pragma unroll
    for (int mi = 0; mi < 4; mi++)
#pragma unroll
        for (int nj = 0; nj < NFRAG; nj++) {
            const int row = m0 + wm * 64 + mi * 16 + lg * 4;
            const int col = n0 + wn * (NFRAG * 16) + nj * 16 + lr;
            const f32x4 v = acc[mi][nj];
            if (FUSE_V && col >= 2 * HID) {
                const int c = col - 2 * HID;            // h = c>>7, d = c&127
                const int b_ = row >> 11, s_ = row & 2047;
                union { ushort_t u[4]; uint2 q; } pk;
#pragma unroll
                for (int j = 0; j < 4; j++) pk.u[j] = f2b(v[j]);
                *(uint2*)&vT[((size_t)(b_ * NH + (c >> 7)) * HD + (c & 127)) * SEQ + s_] = pk.q;
            } else {
                const float sc = (col < scale_cols) ? scale : 1.0f;
#pragma unroll
                for (int j = 0; j < 4; j++) {
                    if (OUT_BF16)
                        ((ushort_t*)C)[(size_t)(row + j) * N + col] = f2b(v[j] * sc);
                    else
                        ((float*)C)[(size_t)(row + j) * N + col] = v[j] * sc;
                }
            }
        }
}

// ------------- flash attention v4: 64KB LDS (Ks single, Vs dbuf) for 2 blocks/CU -------------
__global__ __launch_bounds__(512, 1) void attn_fwd4(const ushort_t* __restrict__ qkvb,
                                                    const ushort_t* __restrict__ vT,
                                                    ushort_t* __restrict__ attnb) {
    __shared__ __align__(16) ushort_t Ks[64 * 128];      // 16 KB (single)
    __shared__ __align__(16) ushort_t Vs[2][128 * 64];   // 32 KB
    __shared__ __align__(16) ushort_t Ps[8][16 * 64];    // 16 KB

    const int t = threadIdx.x;
    const int l = t & 63, w = t >> 6;
    const int lr = l & 15, lg = l >> 4;
    const int pr = blockIdx.x, h = blockIdx.y, b = blockIdx.z;

    const ushort_t* kg = qkvb + (size_t)(b * SEQ) * QKVN + HID + h * HD;
    const ushort_t* vg = vT + (size_t)(b * NH + h) * HD * SEQ;

    char* PsB = (char*)Ps[w];
    const int pssz = ((lr & 7) ^ ((lr >> 3) << 1)) << 4;

    const int kcA = 2 * w, kcB = 2 * w + 1;
    const int krA = 8 * w + (l >> 4), krB = krA + 4;
    const int kcolA = ((l & 15) ^ (l >> 4)) << 3;
    const int kcolB = ((l & 15) ^ (4 + (l >> 4))) << 3;
    const int vrA = 16 * w + (l >> 3), vrB = vrA + 8;
    const int vcol = ((l & 7) ^ (l >> 3)) << 3;

    for (int seg = 0; seg < 2; seg++) {
        const int qt = (seg == 0) ? pr : 15 - pr;
        const int q0 = qt * QB;
        const int q0w = q0 + w * 16;
        const int NT = (q0 + QB) / KVB;

        bf16x8 qf[4];
        {
            const ushort_t* qb = qkvb + (size_t)(b * SEQ + q0w + lr) * QKVN + h * HD + lg * 8;
#pragma unroll
            for (int kc = 0; kc < 4; kc++) qf[kc] = *(const bf16x8*)(qb + kc * 32);
        }
        f32x4 o[8] = {};
        float m[4] = {-3e38f, -3e38f, -3e38f, -3e38f};
        float ls[4] = {0.f, 0.f, 0.f, 0.f};

        __syncthreads();  // previous segment's LDS readers done
        gload_lds16(kg + (size_t)krA * QKVN + kcolA, &Ks[kcA * 512 + l * 8]);
        gload_lds16(kg + (size_t)krB * QKVN + kcolB, &Ks[kcB * 512 + l * 8]);
        gload_lds16(vg + (size_t)vrA * SEQ + vcol,   &Vs[0][kcA * 512 + l * 8]);
        gload_lds16(vg + (size_t)vrB * SEQ + vcol,   &Vs[0][kcB * 512 + l * 8]);

        for (int kt = 0; kt < NT; kt++) {
            const int kv0 = kt * KVB;
            __syncthreads();  // A: K(kt)/V(kt) landed; all prior reads done
            if (kt + 1 < NT) {
                const int nb = (kt + 1) & 1;
                const int nkv = kv0 + KVB;
                gload_lds16(vg + (size_t)vrA * SEQ + nkv + vcol, &Vs[nb][kcA * 512 + l * 8]);
                gload_lds16(vg + (size_t)vrB * SEQ + nkv + vcol, &Vs[nb][kcB * 512 + l * 8]);
            }
            const bool act = (kv0 <= q0w + 15);  // wave-uniform

            f32x4 s[4];
            const int rs = (lr & 7) << 4;
            if (act) {
                const char* KsB = (const char*)Ks;
#pragma unroll
                for (int nf = 0; nf < 4; nf++) {
                    const int r = nf * 16 + lr;
                    s[nf] = (f32x4){0.f, 0.f, 0.f, 0.f};
#pragma unroll
                    for (int kc = 0; kc < 4; kc++) {
                        bf16x8 kf = *(const bf16x8*)(KsB + r * 256 + ((kc * 64 + lg * 16) ^ rs));
                        s[nf] = __builtin_amdgcn_mfma_f32_16x16x32_bf16(qf[kc], kf, s[nf], 0, 0, 0);
                    }
                }
            }
            __syncthreads();  // A2: all waves' QK reads of Ks done -> safe to restage Ks
            if (kt + 1 < NT) {
                const int nkv = kv0 + KVB;
                gload_lds16(kg + (size_t)(nkv + krA) * QKVN + kcolA, &Ks[kcA * 512 + l * 8]);
                gload_lds16(kg + (size_t)(nkv + krB) * QKVN + kcolB, &Ks[kcB * 512 + l * 8]);
            }
            if (!act) continue;

            const char* VsB = (const char*)Vs[kt & 1];
            const bool diag = (kv0 + 63 > q0w);
            float tm[4];
#pragma unroll
            for (int j = 0; j < 4; j++) {
                if (diag) {
                    const int qpos = q0w + lg * 4 + j;
#pragma unroll
                    for (int nf = 0; nf < 4; nf++)
                        if (kv0 + nf * 16 + lr > qpos) s[nf][j] = -3e38f;
                }
                tm[j] = fmaxf(fmaxf(s[0][j], s[1][j]), fmaxf(s[2][j], s[3][j]));
#pragma unroll
                for (int mk = 1; mk < 16; mk <<= 1)
                    tm[j] = fmaxf(tm[j], __shfl_xor(tm[j], mk, 64));
            }

            float grow = fmaxf(fmaxf(tm[0] - m[0], tm[1] - m[1]),
                               fmaxf(tm[2] - m[2], tm[3] - m[3]));
            if (!__all(grow <= 8.0f)) {
#pragma unroll
                for (int j = 0; j < 4; j++) {
                    const float mn = fmaxf(m[j], tm[j]);
                    const float fac = exp2f((m[j] - mn) * 1.44269504f);
                    m[j] = mn; ls[j] *= fac;
#pragma unroll
                    for (int nf2 = 0; nf2 < 8; nf2++) o[nf2][j] *= fac;
                }
            }

#pragma unroll
            for (int j = 0; j < 4; j++) {
                const int row = lg * 4 + j;
                const int rsz = ((row & 7) ^ ((row >> 3) << 1)) << 4;
                float psum = 0.f;
#pragma unroll
                for (int nf = 0; nf < 4; nf++) {
                    float p = exp2f((s[nf][j] - m[j]) * 1.44269504f);
                    psum += p;
                    union { float f; unsigned u; } cv; cv.f = p;
                    *(ushort_t*)(PsB + row * 128 + ((nf * 32 + lr * 2) ^ rsz)) = (ushort_t)(cv.u >> 16);
                }
                ls[j] += psum;
            }

            bf16x8 pa0 = *(const bf16x8*)(PsB + lr * 128 + ((lg * 16) ^ pssz));
            bf16x8 pa1 = *(const bf16x8*)(PsB + lr * 128 + ((64 + lg * 16) ^ pssz));
#pragma unroll
            for (int nf2 = 0; nf2 < 8; nf2++) {
                const int vr2 = nf2 * 16 + lr;
                bf16x8 vb0 = *(const bf16x8*)(VsB + vr2 * 128 + ((lg * 16) ^ rs));
                bf16x8 vb1 = *(const bf16x8*)(VsB + vr2 * 128 + ((64 + lg * 16) ^ rs));
                o[nf2] = __builtin_amdgcn_mfma_f32_16x16x32_bf16(pa0, vb0, o[nf2], 0, 0, 0);
                o[nf2] = __builtin_amdgcn_mfma_f32_16x16x32_bf16(pa1, vb1, o[nf2], 0, 0, 0);
            }
        }

        float inv[4];
#pragma unroll
        for (int j = 0; j < 4; j++) {
            float sum = ls[j];
#pragma unroll
            for (int mk = 1; mk < 16; mk <<= 1) sum += __shfl_xor(sum, mk, 64);
            inv[j] = 1.0f / sum;
        }
        ushort_t* ob = attnb + (size_t)(b * SEQ + q0w) * HID + h * HD;
#pragma unroll
        for (int nf2 = 0; nf2 < 8; nf2++)
#pragma unroll
            for (int j = 0; j < 4; j++)
                ob[(size_t)(lg * 4 + j) * HID + nf2 * 16 + lr] = f2b(o[nf2][j] * inv[j]);
    }
}

extern "C" void kernel_launch(void* const* d_in, const int* in_sizes, int n_in,
                              void* d_out, int out_size, void* d_ws, size_t ws_size,
                              hipStream_t stream) {
    const float* x     = (const float*)d_in[0];
    const float* w_qkv = (const float*)d_in[1];
    const float* w_out = (const float*)d_in[2];
    float* out = (float*)d_out;

    // Layout note: every GEMM-staged buffer is followed by another mapped buffer —
    // dead tail stages read <=192B past the end (never consumed).
    char* ws = (char*)d_ws;
    ushort_t* xb    = (ushort_t*)(ws);                 // 4096x2048 bf16
    ushort_t* wqkvT = (ushort_t*)(ws + 16777216);      // 6144x2048 bf16
    ushort_t* woutT = (ushort_t*)(ws + 41943040);      // 2048x2048 bf16
    ushort_t* qkvb  = (ushort_t*)(ws + 50331648);      // 4096x6144 bf16 (V third unused)
    ushort_t* attnb = (ushort_t*)(ws + 100663296);     // 4096x2048 bf16
    ushort_t* vT    = (ushort_t*)(ws + 117440512);     // [b][h][d][s] bf16

    const int M = 2 * SEQ;  // 4096

    castbf<<<(M * HID) / (256 * 8), 256, 0, stream>>>(x, xb, M * HID);
    transcast<<<dim3(QKVN / 32, HID / 32), 256, 0, stream>>>(w_qkv, wqkvT, HID, QKVN);
    transcast<<<dim3(HID / 32, HID / 32), 256, 0, stream>>>(w_out, woutT, HID, HID);

    // qkv = x @ w_qkv, Q pre-scaled; V written transposed to vT (transV fused away)
    gemmpl<6, true, true><<<(M / 128) * (QKVN / 384), 512, 0, stream>>>(
        xb, wqkvT, qkvb, vT, M, QKVN, HID, HID, 0.08838834764831845f);

    attn_fwd4<<<dim3(8, NH, 2), 512, 0, stream>>>(qkvb, vT, attnb);

    // out = attn @ w_out; 128x256, 256 blocks = 1 round
    gemmpl<4, false, false><<<(M / 128) * (HID / 256), 512, 0, stream>>>(
        attnb, woutT, out, nullptr, M, HID, HID, 0, 1.0f);
}

// Round 19
// 249.674 us; speedup vs baseline: 1.1072x; 1.0006x over previous
//
#include <hip/hip_runtime.h>
#include <hip/hip_bf16.h>

typedef __attribute__((ext_vector_type(8))) short bf16x8;
typedef __attribute__((ext_vector_type(4))) float f32x4;
typedef unsigned short ushort_t;

#define HID 2048
#define QKVN 6144
#define SEQ 2048
#define NH 16
#define HD 128
#define QB 128
#define KVB 64

#define GLOBAL_AS __attribute__((address_space(1)))
#define LDS_AS __attribute__((address_space(3)))
typedef LDS_AS const char lds_char;

__device__ __forceinline__ void gload_lds16(const ushort_t* g, ushort_t* l) {
    __builtin_amdgcn_global_load_lds((const GLOBAL_AS unsigned int*)g,
                                     (LDS_AS unsigned int*)l, 16, 0, 0);
}

// ds_read_b128 with compile-time offset immediate; opaque to waitcnt pass (r7 win).
template <int OFF>
__device__ __forceinline__ bf16x8 dsr128o(lds_char* p) {
    bf16x8 r;
    asm volatile("ds_read_b128 %0, %1 offset:%2" : "=v"(r) : "v"(p), "i"(OFF));
    return r;
}

__device__ __forceinline__ ushort_t f2b(float f) {
    union { float f; unsigned int u; } x; x.f = f;
    unsigned int r = x.u + 0x7fffu + ((x.u >> 16) & 1u);  // RNE
    return (ushort_t)(r >> 16);
}

#define BARX() asm volatile("s_barrier" ::: "memory")
#define LGKM0() asm volatile("s_waitcnt lgkmcnt(0)" ::: "memory")
#define VMC0() asm volatile("s_waitcnt vmcnt(0)" ::: "memory")

// ---------------- cast fp32 -> bf16 (vectorized) ----------------
__global__ __launch_bounds__(256) void castbf(const float* __restrict__ in,
                                              ushort_t* __restrict__ out, int n) {
    int i = (blockIdx.x * 256 + threadIdx.x) * 8;
    if (i >= n) return;
    float4 a = *(const float4*)(in + i);
    float4 b = *(const float4*)(in + i + 4);
    union { ushort_t u[8]; uint4 v; } r;
    r.u[0] = f2b(a.x); r.u[1] = f2b(a.y); r.u[2] = f2b(a.z); r.u[3] = f2b(a.w);
    r.u[4] = f2b(b.x); r.u[5] = f2b(b.y); r.u[6] = f2b(b.z); r.u[7] = f2b(b.w);
    *(uint4*)(out + i) = r.v;
}

// ------------- transpose + cast: fp32 K x N  ->  bf16 N x K -------------
__global__ __launch_bounds__(256) void transcast(const float* __restrict__ in,
                                                 ushort_t* __restrict__ out,
                                                 int Kd, int Nd) {
    __shared__ float tile[32][33];
    int tx = threadIdx.x & 31, ty = threadIdx.x >> 5;
    int n0 = blockIdx.x * 32, k0 = blockIdx.y * 32;
    for (int j = 0; j < 4; j++)
        tile[ty + 8 * j][tx] = in[(size_t)(k0 + ty + 8 * j) * Nd + n0 + tx];
    __syncthreads();
    for (int j = 0; j < 4; j++)
        out[(size_t)(n0 + ty + 8 * j) * Kd + k0 + tx] = f2b(tile[tx][ty + 8 * j]);
}

// ------------- GEMM 128x(NFRAG*64), BK=32, 3 buffers, compile-time schedule -------------
// r15/r18 structure. r19 change: the pre-MFMA sched_barrier(0) is REMOVED so the
// scheduler may interleave the (independent) asm ds_reads / stage loads with the
// MFMA cluster — previously all 80 block ds_reads issued in a post-barrier burst,
// saturating the LDS queue while the matrix pipe idled. Consumption safety (rule 18)
// is preserved by the TOP-of-step lgkmcnt(0)+sched_barrier(0): MFMAs cannot hoist
// above that full fence, and MFMAS(k) has no dependence on READS(k+1)/STAGES.
template <int NFRAG, bool OUT_BF16, bool FUSE_V>
__global__ __launch_bounds__(512, 1) void gemmpl(const ushort_t* __restrict__ A,
                                                 const ushort_t* __restrict__ BT,
                                                 void* __restrict__ C,
                                                 ushort_t* __restrict__ vT,
                                                 int M, int N, int K,
                                                 int scale_cols, float scale) {
    __shared__ __align__(16) ushort_t As[3][128 * 32];
    __shared__ __align__(16) ushort_t Bs[3][NFRAG * 64 * 32];

    const int t = threadIdx.x;
    const int l = t & 63, w = t >> 6;
    const int wm = w >> 2, wn = w & 3;
    const int lr = l & 15, lg = l >> 4;

    // XCD-aware bijective swizzle (grids 512 / 256, both % 8 == 0)
    const int nwg = gridDim.x;
    const int cpx = nwg >> 3;
    const int swb = (blockIdx.x & 7) * cpx + (blockIdx.x >> 3);
    const int BN = NFRAG * 64;
    const int NTN = N / BN;
    const int m0 = (swb / NTN) << 7, n0 = (swb % NTN) * BN;

    f32x4 acc[4][NFRAG] = {};
    bf16x8 afA[4], bfA[NFRAG], afB[4], bfB[NFRAG];

    // ---- stage pointers (swizzled source granule baked in); advance by literals ----
    const int sr = t >> 2, sg = (t & 3) ^ ((t >> 3) & 3);
    const ushort_t* aP  = A  + (size_t)(m0 + sr) * K + (sg << 3);
    const ushort_t* bP0 = BT + (size_t)(n0 + sr) * K + (sg << 3);
    const ushort_t* bP1 = BT + (size_t)(n0 + 128 + sr) * K + (sg << 3);
    const ushort_t* bP2 = (NFRAG == 6) ? BT + (size_t)(n0 + 256 + sr) * K + (sg << 3) : nullptr;

    // ---- precomputed LDS read bases ----
    const int co_ = (lg ^ ((lr >> 1) & 3)) << 4;
    const int aoff = (wm * 64 + lr) * 64 + co_;
    const int boff = (wn * (NFRAG * 16) + lr) * 64 + co_;
    lds_char* aR0 = (lds_char*)&As[0][0] + aoff;
    lds_char* aR1 = (lds_char*)&As[1][0] + aoff;
    lds_char* aR2 = (lds_char*)&As[2][0] + aoff;
    lds_char* bR0 = (lds_char*)&Bs[0][0] + boff;
    lds_char* bR1 = (lds_char*)&Bs[1][0] + boff;
    lds_char* bR2 = (lds_char*)&Bs[2][0] + boff;

#define GLO(G, L)                                                               \
    __builtin_amdgcn_global_load_lds((const GLOBAL_AS unsigned int*)(G),        \
                                     (LDS_AS unsigned int*)(L), 16, 0, 0)

// OFFE: element offset (literal) from current stage base = (tile - base_tile)*32
#define STAGES(SB, OFFE)                                                        \
    do {                                                                        \
        GLO(aP + (OFFE),  &As[SB][t * 8]);                                      \
        GLO(bP0 + (OFFE), &Bs[SB][t * 8]);                                      \
        GLO(bP1 + (OFFE), &Bs[SB][(512 + t) * 8]);                              \
        if constexpr (NFRAG == 6) GLO(bP2 + (OFFE), &Bs[SB][(1024 + t) * 8]);   \
    } while (0)

#define READS(AF, BF, AR, BR)                                                   \
    do {                                                                        \
        AF[0] = dsr128o<0>(AR);    AF[1] = dsr128o<1024>(AR);                   \
        AF[2] = dsr128o<2048>(AR); AF[3] = dsr128o<3072>(AR);                   \
        BF[0] = dsr128o<0>(BR);    BF[1] = dsr128o<1024>(BR);                   \
        BF[2] = dsr128o<2048>(BR); BF[3] = dsr128o<3072>(BR);                   \
        if constexpr (NFRAG == 6) {                                             \
            BF[4] = dsr128o<4096>(BR); BF[5] = dsr128o<5120>(BR);               \
        }                                                                       \
    } while (0)

#define VMCL()                                                                      \
    do { if constexpr (NFRAG == 6) asm volatile("s_waitcnt vmcnt(4)" ::: "memory"); \
         else                      asm volatile("s_waitcnt vmcnt(3)" ::: "memory"); } while (0)
#define VMC2L()                                                                     \
    do { if constexpr (NFRAG == 6) asm volatile("s_waitcnt vmcnt(8)" ::: "memory"); \
         else                      asm volatile("s_waitcnt vmcnt(6)" ::: "memory"); } while (0)

#define MFMAS(AF, BF)                                                           \
    do {                                                                        \
        __builtin_amdgcn_s_setprio(1);                                          \
        _Pragma("unroll") for (int mi = 0; mi < 4; mi++)                        \
            _Pragma("unroll") for (int nj = 0; nj < NFRAG; nj++)                \
                acc[mi][nj] = __builtin_amdgcn_mfma_f32_16x16x32_bf16(          \
                    AF[mi], BF[nj], acc[mi][nj], 0, 0, 0);                      \
        __builtin_amdgcn_s_setprio(0);                                          \
    } while (0)

// r19 step: no pre-MFMA sched_barrier — scheduler may interleave reads/stages
// with the MFMA cluster. Top fence (lgkm0 + sched_barrier) still bounds hoisting.
#define STEP(SB, AR, BR, AFU, BFU, AFV, BFV, OFFE)                              \
    {                                                                           \
        LGKM0();                                                                \
        __builtin_amdgcn_sched_barrier(0);                                      \
        BARX();                                                                 \
        READS(AFV, BFV, AR, BR);                                                \
        STAGES(SB, OFFE);                                                       \
        MFMAS(AFU, BFU);                                                        \
        VMCL();                                                                 \
    }

    // prologue: stage tiles 0,1,2; drain tile0; barrier; read frags(0); drain tile1
    STAGES(0, 0);
    STAGES(1, 32);
    STAGES(2, 64);
    aP += 96; bP0 += 96; bP1 += 96;
    if constexpr (NFRAG == 6) bP2 += 96;
    VMC2L();
    BARX();
    READS(afA, bfA, aR0, bR0);
    VMCL();

    // 10 blocks of 6 steps (kt = 6it .. 6it+5); stage base corresponds to kt=6it+3
#pragma unroll 1
    for (int it = 0; it < 10; it++) {
        STEP(0, aR1, bR1, afA, bfA, afB, bfB, 0);
        STEP(1, aR2, bR2, afB, bfB, afA, bfA, 32);
        STEP(2, aR0, bR0, afA, bfA, afB, bfB, 64);
        STEP(0, aR1, bR1, afB, bfB, afA, bfA, 96);
        STEP(1, aR2, bR2, afA, bfA, afB, bfB, 128);
        STEP(2, aR0, bR0, afB, bfB, afA, bfA, 160);
        aP += 192; bP0 += 192; bP1 += 192;
        if constexpr (NFRAG == 6) bP2 += 192;
    }
    // tail: kt = 60,61,62,63 (stage base at tile 63; 61/62 re-stage tile 63, dead)
    STEP(0, aR1, bR1, afA, bfA, afB, bfB, 0);
    STEP(1, aR2, bR2, afB, bfB, afA, bfA, 0);
    STEP(2, aR0, bR0, afA, bfA, afB, bfB, 0);
    LGKM0();
    __builtin_amdgcn_sched_barrier(0);
    VMC0();
    MFMAS(afB, bfB);

#undef STEP
#undef MFMAS
#undef VMCL
#undef VMC2L
#undef READS
#undef STAGES
#undef GLO

    // epilogue
#pragma unroll
    for (int mi = 0; mi < 4; mi++)
#pragma unroll
        for (int nj = 0; nj < NFRAG; nj++) {
            const int row = m0 + wm * 64 + mi * 16 + lg * 4;
            const int col = n0 + wn * (NFRAG * 16) + nj * 16 + lr;
            const f32x4 v = acc[mi][nj];
            if (FUSE_V && col >= 2 * HID) {
                const int c = col - 2 * HID;            // h = c>>7, d = c&127
                const int b_ = row >> 11, s_ = row & 2047;
                union { ushort_t u[4]; uint2 q; } pk;
#pragma unroll
                for (int j = 0; j < 4; j++) pk.u[j] = f2b(v[j]);
                *(uint2*)&vT[((size_t)(b_ * NH + (c >> 7)) * HD + (c & 127)) * SEQ + s_] = pk.q;
            } else {
                const float sc = (col < scale_cols) ? scale : 1.0f;
#pragma unroll
                for (int j = 0; j < 4; j++) {
                    if (OUT_BF16)
                        ((ushort_t*)C)[(size_t)(row + j) * N + col] = f2b(v[j] * sc);
                    else
                        ((float*)C)[(size_t)(row + j) * N + col] = v[j] * sc;
                }
            }
        }
}

// ------------- flash attention v4: 64KB LDS (Ks single, Vs dbuf) for 2 blocks/CU -------------
__global__ __launch_bounds__(512, 1) void attn_fwd4(const ushort_t* __restrict__ qkvb,
                                                    const ushort_t* __restrict__ vT,
                                                    ushort_t* __restrict__ attnb) {
    __shared__ __align__(16) ushort_t Ks[64 * 128];      // 16 KB (single)
    __shared__ __align__(16) ushort_t Vs[2][128 * 64];   // 32 KB
    __shared__ __align__(16) ushort_t Ps[8][16 * 64];    // 16 KB

    const int t = threadIdx.x;
    const int l = t & 63, w = t >> 6;
    const int lr = l & 15, lg = l >> 4;
    const int pr = blockIdx.x, h = blockIdx.y, b = blockIdx.z;

    const ushort_t* kg = qkvb + (size_t)(b * SEQ) * QKVN + HID + h * HD;
    const ushort_t* vg = vT + (size_t)(b * NH + h) * HD * SEQ;

    char* PsB = (char*)Ps[w];
    const int pssz = ((lr & 7) ^ ((lr >> 3) << 1)) << 4;

    const int kcA = 2 * w, kcB = 2 * w + 1;
    const int krA = 8 * w + (l >> 4), krB = krA + 4;
    const int kcolA = ((l & 15) ^ (l >> 4)) << 3;
    const int kcolB = ((l & 15) ^ (4 + (l >> 4))) << 3;
    const int vrA = 16 * w + (l >> 3), vrB = vrA + 8;
    const int vcol = ((l & 7) ^ (l >> 3)) << 3;

    for (int seg = 0; seg < 2; seg++) {
        const int qt = (seg == 0) ? pr : 15 - pr;
        const int q0 = qt * QB;
        const int q0w = q0 + w * 16;
        const int NT = (q0 + QB) / KVB;

        bf16x8 qf[4];
        {
            const ushort_t* qb = qkvb + (size_t)(b * SEQ + q0w + lr) * QKVN + h * HD + lg * 8;
#pragma unroll
            for (int kc = 0; kc < 4; kc++) qf[kc] = *(const bf16x8*)(qb + kc * 32);
        }
        f32x4 o[8] = {};
        float m[4] = {-3e38f, -3e38f, -3e38f, -3e38f};
        float ls[4] = {0.f, 0.f, 0.f, 0.f};

        __syncthreads();  // previous segment's LDS readers done
        gload_lds16(kg + (size_t)krA * QKVN + kcolA, &Ks[kcA * 512 + l * 8]);
        gload_lds16(kg + (size_t)krB * QKVN + kcolB, &Ks[kcB * 512 + l * 8]);
        gload_lds16(vg + (size_t)vrA * SEQ + vcol,   &Vs[0][kcA * 512 + l * 8]);
        gload_lds16(vg + (size_t)vrB * SEQ + vcol,   &Vs[0][kcB * 512 + l * 8]);

        for (int kt = 0; kt < NT; kt++) {
            const int kv0 = kt * KVB;
            __syncthreads();  // A: K(kt)/V(kt) landed; all prior reads done
            if (kt + 1 < NT) {
                const int nb = (kt + 1) & 1;
                const int nkv = kv0 + KVB;
                gload_lds16(vg + (size_t)vrA * SEQ + nkv + vcol, &Vs[nb][kcA * 512 + l * 8]);
                gload_lds16(vg + (size_t)vrB * SEQ + nkv + vcol, &Vs[nb][kcB * 512 + l * 8]);
            }
            const bool act = (kv0 <= q0w + 15);  // wave-uniform

            f32x4 s[4];
            const int rs = (lr & 7) << 4;
            if (act) {
                const char* KsB = (const char*)Ks;
#pragma unroll
                for (int nf = 0; nf < 4; nf++) {
                    const int r = nf * 16 + lr;
                    s[nf] = (f32x4){0.f, 0.f, 0.f, 0.f};
#pragma unroll
                    for (int kc = 0; kc < 4; kc++) {
                        bf16x8 kf = *(const bf16x8*)(KsB + r * 256 + ((kc * 64 + lg * 16) ^ rs));
                        s[nf] = __builtin_amdgcn_mfma_f32_16x16x32_bf16(qf[kc], kf, s[nf], 0, 0, 0);
                    }
                }
            }
            __syncthreads();  // A2: all waves' QK reads of Ks done -> safe to restage Ks
            if (kt + 1 < NT) {
                const int nkv = kv0 + KVB;
                gload_lds16(kg + (size_t)(nkv + krA) * QKVN + kcolA, &Ks[kcA * 512 + l * 8]);
                gload_lds16(kg + (size_t)(nkv + krB) * QKVN + kcolB, &Ks[kcB * 512 + l * 8]);
            }
            if (!act) continue;

            const char* VsB = (const char*)Vs[kt & 1];
            const bool diag = (kv0 + 63 > q0w);
            float tm[4];
#pragma unroll
            for (int j = 0; j < 4; j++) {
                if (diag) {
                    const int qpos = q0w + lg * 4 + j;
#pragma unroll
                    for (int nf = 0; nf < 4; nf++)
                        if (kv0 + nf * 16 + lr > qpos) s[nf][j] = -3e38f;
                }
                tm[j] = fmaxf(fmaxf(s[0][j], s[1][j]), fmaxf(s[2][j], s[3][j]));
#pragma unroll
                for (int mk = 1; mk < 16; mk <<= 1)
                    tm[j] = fmaxf(tm[j], __shfl_xor(tm[j], mk, 64));
            }

            float grow = fmaxf(fmaxf(tm[0] - m[0], tm[1] - m[1]),
                               fmaxf(tm[2] - m[2], tm[3] - m[3]));
            if (!__all(grow <= 8.0f)) {
#pragma unroll
                for (int j = 0; j < 4; j++) {
                    const float mn = fmaxf(m[j], tm[j]);
                    const float fac = exp2f((m[j] - mn) * 1.44269504f);
                    m[j] = mn; ls[j] *= fac;
#pragma unroll
                    for (int nf2 = 0; nf2 < 8; nf2++) o[nf2][j] *= fac;
                }
            }

#pragma unroll
            for (int j = 0; j < 4; j++) {
                const int row = lg * 4 + j;
                const int rsz = ((row & 7) ^ ((row >> 3) << 1)) << 4;
                float psum = 0.f;
#pragma unroll
                for (int nf = 0; nf < 4; nf++) {
                    float p = exp2f((s[nf][j] - m[j]) * 1.44269504f);
                    psum += p;
                    union { float f; unsigned u; } cv; cv.f = p;
                    *(ushort_t*)(PsB + row * 128 + ((nf * 32 + lr * 2) ^ rsz)) = (ushort_t)(cv.u >> 16);
                }
                ls[j] += psum;
            }

            bf16x8 pa0 = *(const bf16x8*)(PsB + lr * 128 + ((lg * 16) ^ pssz));
            bf16x8 pa1 = *(const bf16x8*)(PsB + lr * 128 + ((64 + lg * 16) ^ pssz));
#pragma unroll
            for (int nf2 = 0; nf2 < 8; nf2++) {
                const int vr2 = nf2 * 16 + lr;
                bf16x8 vb0 = *(const bf16x8*)(VsB + vr2 * 128 + ((lg * 16) ^ rs));
                bf16x8 vb1 = *(const bf16x8*)(VsB + vr2 * 128 + ((64 + lg * 16) ^ rs));
                o[nf2] = __builtin_amdgcn_mfma_f32_16x16x32_bf16(pa0, vb0, o[nf2], 0, 0, 0);
                o[nf2] = __builtin_amdgcn_mfma_f32_16x16x32_bf16(pa1, vb1, o[nf2], 0, 0, 0);
            }
        }

        float inv[4];
#pragma unroll
        for (int j = 0; j < 4; j++) {
            float sum = ls[j];
#pragma unroll
            for (int mk = 1; mk < 16; mk <<= 1) sum += __shfl_xor(sum, mk, 64);
            inv[j] = 1.0f / sum;
        }
        ushort_t* ob = attnb + (size_t)(b * SEQ + q0w) * HID + h * HD;
#pragma unroll
        for (int nf2 = 0; nf2 < 8; nf2++)
#pragma unroll
            for (int j = 0; j < 4; j++)
                ob[(size_t)(lg * 4 + j) * HID + nf2 * 16 + lr] = f2b(o[nf2][j] * inv[j]);
    }
}

extern "C" void kernel_launch(void* const* d_in, const int* in_sizes, int n_in,
                              void* d_out, int out_size, void* d_ws, size_t ws_size,
                              hipStream_t stream) {
    const float* x     = (const float*)d_in[0];
    const float* w_qkv = (const float*)d_in[1];
    const float* w_out = (const float*)d_in[2];
    float* out = (float*)d_out;

    // Layout note: every GEMM-staged buffer is followed by another mapped buffer —
    // dead tail stages read <=192B past the end (never consumed).
    char* ws = (char*)d_ws;
    ushort_t* xb    = (ushort_t*)(ws);                 // 4096x2048 bf16
    ushort_t* wqkvT = (ushort_t*)(ws + 16777216);      // 6144x2048 bf16
    ushort_t* woutT = (ushort_t*)(ws + 41943040);      // 2048x2048 bf16
    ushort_t* qkvb  = (ushort_t*)(ws + 50331648);      // 4096x6144 bf16 (V third unused)
    ushort_t* attnb = (ushort_t*)(ws + 100663296);     // 4096x2048 bf16
    ushort_t* vT    = (ushort_t*)(ws + 117440512);     // [b][h][d][s] bf16

    const int M = 2 * SEQ;  // 4096

    castbf<<<(M * HID) / (256 * 8), 256, 0, stream>>>(x, xb, M * HID);
    transcast<<<dim3(QKVN / 32, HID / 32), 256, 0, stream>>>(w_qkv, wqkvT, HID, QKVN);
    transcast<<<dim3(HID / 32, HID / 32), 256, 0, stream>>>(w_out, woutT, HID, HID);

    // qkv = x @ w_qkv, Q pre-scaled; V written transposed to vT (transV fused away)
    gemmpl<6, true, true><<<(M / 128) * (QKVN / 384), 512, 0, stream>>>(
        xb, wqkvT, qkvb, vT, M, QKVN, HID, HID, 0.08838834764831845f);

    attn_fwd4<<<dim3(8, NH, 2), 512, 0, stream>>>(qkvb, vT, attnb);

    // out = attn @ w_out; 128x256, 256 blocks = 1 round
    gemmpl<4, false, false><<<(M / 128) * (HID / 256), 512, 0, stream>>>(
        attnb, woutT, out, nullptr, M, HID, HID, 0, 1.0f);
}